// Round 7
// baseline (121.212 us; speedup 1.0000x reference)
//
#include <hip/hip_runtime.h>
#include <cstdint>

// Poincare-ball MLR:  out[row][n] = S_n * asinh( lam_row * inner[row][n] * A_n - (lam_row-1) * B_n )
//   inner = X @ Z  (bf16 MFMA),  lam_row = 2/(1 - ||x_row||^2)
//   A_n = cosh(2 r_n)/znorm_n,  B_n = sinh(2 r_n),  S_n = 2 znorm_n   (c = 1)
//
// R6 = R5b + de-scattered epilogue. After the MFMA loop the 32KB Zt LDS region
// is dead: behind a second __syncthreads each wave recycles an 8KB slice as a
// transpose buffer (32 swizzled ds_write_b32, exactly 2-way bank aliasing =
// free), reads back 8x ds_read_b128, computes asinh in transposed layout
// (lane owns 4 contiguous cols -> constants are 3 coalesced float4 loads) and
// stores 8x fully-coalesced 1KB global_store_dwordx4. Block stays 32KB LDS ->
// 5 blocks/CU (20 waves/CU).

typedef __attribute__((ext_vector_type(8))) short short8;   // 8 bf16 = 4 VGPRs (MFMA A/B frag)
typedef __attribute__((ext_vector_type(4))) float floatx4;  // MFMA C/D frag

#define D 128

__device__ inline unsigned bf16_rhu(float f) {   // round-half-up to bf16, bit trick (2 VALU)
    return (__float_as_uint(f) + 0x8000u) >> 16;
}
__device__ inline unsigned pack2(float lo, float hi) {
    return bf16_rhu(lo) | (bf16_rhu(hi) << 16);
}

// ---------------- prep: PRE-SWIZZLED bf16 Zt + per-col constant arrays ----------------
// zt_sw chunk layout: 16B chunk (row, c) stored at chunk index row*16 + (c ^ (row&7)),
// so a linear global_load_lds stage reproduces the swizzled LDS layout.
// An = cosh(2r)/zn, Bn = sinh(2r), Sn = 2*zn*ln2 (ln2 folded: asinh via log2)
__global__ void hmlr_prep(const float* __restrict__ z, const float* __restrict__ r,
                          unsigned short* __restrict__ zt_sw, float* __restrict__ An,
                          float* __restrict__ Bn, float* __restrict__ Sn) {
    int n = blockIdx.x;
    int k = threadIdx.x;
    float v = z[k * D + n];                          // column n of Z
    int c = k >> 3, p = k & 7;
    zt_sw[n * D + ((c ^ (n & 7)) << 3) + p] = (unsigned short)bf16_rhu(v);
    float pw = v * v;
    #pragma unroll
    for (int off = 32; off >= 1; off >>= 1) pw += __shfl_down(pw, off, 64);
    __shared__ float tmp[2];
    if ((k & 63) == 0) tmp[k >> 6] = pw;
    __syncthreads();
    if (k == 0) {
        float ss = tmp[0] + tmp[1];
        float zn = fmaxf(sqrtf(ss), 1e-15f);
        float tc = 2.0f * r[n];                      // 2*sqrt(c)*r, c=1
        An[n] = coshf(tc) / zn;
        Bn[n] = sinhf(tc);
        Sn[n] = 2.0f * zn * 0.69314718055994531f;
    }
}

// ---------------- main: 2048 blocks x 256 threads, 4 waves x 16 rows = 64 rows/block ------
__global__ __launch_bounds__(256, 5) void hmlr_main(const float* __restrict__ x,
                                                    const unsigned short* __restrict__ zt_sw,
                                                    const float* __restrict__ An,
                                                    const float* __restrict__ Bn,
                                                    const float* __restrict__ Sn,
                                                    float* __restrict__ out) {
    __shared__ __align__(16) unsigned char lds[32768];   // Zt (phase 1) / transpose buf (phase 2)

    const int t    = threadIdx.x;
    const int w    = t >> 6;         // wave 0..3
    const int l    = t & 63;
    const int quad = l >> 4;         // 0..3
    const int l15  = l & 15;
    const int l7   = l & 7;

    // ---- Zt -> LDS: async direct-to-LDS, 1KB per wave-instruction, 8 per wave ----
#if __has_builtin(__builtin_amdgcn_global_load_lds)
    #pragma unroll
    for (int i = 0; i < 8; ++i) {
        int ci = w * 512 + i * 64 + l;               // 16B chunk index 0..2047
        __builtin_amdgcn_global_load_lds(
            (const __attribute__((address_space(1))) unsigned int*)(zt_sw + (ci << 3)),
            (__attribute__((address_space(3))) unsigned int*)(lds + ((w * 512 + i * 64) << 4)),
            16, 0, 0);
    }
#else
    #pragma unroll
    for (int i = 0; i < 8; ++i) {
        int ci = w * 512 + i * 64 + l;
        *reinterpret_cast<uint4*>(&lds[ci << 4]) = reinterpret_cast<const uint4*>(zt_sw)[ci];
    }
#endif
    __syncthreads();

    // ---- X direct from global in MFMA A-layout: lane(m=l15) reads row's k-octets ----
    const int rowbase = blockIdx.x * 64 + w * 16;    // this wave's 16 rows
    const float* xrow = x + (size_t)(rowbase + l15) * D + (quad << 3);
    float4 xv[8];
    #pragma unroll
    for (int kc = 0; kc < 4; ++kc) {
        xv[2 * kc]     = *reinterpret_cast<const float4*>(xrow + (kc << 5));
        xv[2 * kc + 1] = *reinterpret_cast<const float4*>(xrow + (kc << 5) + 4);
    }

    // ---- ||x_row||^2 fp32 (pre-cast): lane partial + combine quads sharing l15 ----
    float ssq = 0.f;
    #pragma unroll
    for (int i = 0; i < 8; ++i)
        ssq += xv[i].x * xv[i].x + xv[i].y * xv[i].y + xv[i].z * xv[i].z + xv[i].w * xv[i].w;
    ssq += __shfl_xor(ssq, 16);
    ssq += __shfl_xor(ssq, 32);      // lane l now holds ssq of row (rowbase + (l&15))

    // ---- bf16 A-frags, bit-trick pack ----
    short8 afrag[4];
    #pragma unroll
    for (int kc = 0; kc < 4; ++kc) {
        union { short8 s8; unsigned u[4]; } af;
        af.u[0] = pack2(xv[2 * kc].x,     xv[2 * kc].y);
        af.u[1] = pack2(xv[2 * kc].z,     xv[2 * kc].w);
        af.u[2] = pack2(xv[2 * kc + 1].x, xv[2 * kc + 1].y);
        af.u[3] = pack2(xv[2 * kc + 1].z, xv[2 * kc + 1].w);
        afrag[kc] = af.s8;
    }

    // ---- MFMA 16x16x32 bf16, per-kc B preload (8 frags in regs -> ILP) ----
    floatx4 acc[8];
    #pragma unroll
    for (int nt = 0; nt < 8; ++nt) acc[nt] = (floatx4){0.f, 0.f, 0.f, 0.f};

    #pragma unroll
    for (int kc = 0; kc < 4; ++kc) {
        short8 b[8];
        #pragma unroll
        for (int nt = 0; nt < 8; ++nt)
            b[nt] = *reinterpret_cast<const short8*>(
                &lds[((nt * 16 + l15) << 8) + (((quad + (kc << 2)) ^ l7) << 4)]);
        #pragma unroll
        for (int nt = 0; nt < 8; ++nt)
            acc[nt] = __builtin_amdgcn_mfma_f32_16x16x32_bf16(afrag[kc], b[nt], acc[nt], 0, 0, 0);
    }

    // ---- Zt region now dead for the whole block: recycle as per-wave transpose buffer ----
    __syncthreads();
    unsigned char* eb = lds + (w << 13);             // wave-private 8KB slice

    // scatter acc into transposed staging: row-major fp32 [16][128], XOR-swizzled
    // 16B chunks (chunk ^ (row&7)). Bank aliasing across the wave: exactly 2-way (free).
    #pragma unroll
    for (int reg = 0; reg < 4; ++reg) {
        int row = (quad << 2) + reg;
        int r7  = row & 7;
        #pragma unroll
        for (int nt = 0; nt < 8; ++nt) {
            int col  = l15 + (nt << 4);
            int byte = (row << 9) + (((col >> 2) ^ r7) << 4) + ((col & 3) << 2);
            *reinterpret_cast<float*>(&eb[byte]) = acc[nt][reg];
        }
    }

    // per-lane constants for the transposed layout: 4 contiguous cols
    const int col0 = (l & 31) << 2;
    float4 A4 = *reinterpret_cast<const float4*>(An + col0);
    float4 B4 = *reinterpret_cast<const float4*>(Bn + col0);
    float4 S4 = *reinterpret_cast<const float4*>(Sn + col0);

    // coalesced readback (same-wave DS ordering, no barrier) + asinh + 1KB stores
    float4* outv = reinterpret_cast<float4*>(out + (size_t)rowbase * D);
    #pragma unroll
    for (int j = 0; j < 8; ++j) {
        int rl = (j << 1) + (l >> 5);                // wave-local row 0..15
        float4 v = *reinterpret_cast<const float4*>(
            &eb[(rl << 9) + (((l & 31) ^ (rl & 7)) << 4)]);
        float rss = __shfl(ssq, rl);                 // row rl's ||x||^2 (bpermute)
        float lam = 2.0f / (1.0f - rss);
        float lm1 = lam - 1.0f;
        float4 res;
        {
            float arg = __fmaf_rn(lam * v.x, A4.x, -lm1 * B4.x);
            float a = fabsf(arg);
            res.x = copysignf(__log2f(a + __fsqrt_rn(__fmaf_rn(a, a, 1.0f))), arg) * S4.x;
        }
        {
            float arg = __fmaf_rn(lam * v.y, A4.y, -lm1 * B4.y);
            float a = fabsf(arg);
            res.y = copysignf(__log2f(a + __fsqrt_rn(__fmaf_rn(a, a, 1.0f))), arg) * S4.y;
        }
        {
            float arg = __fmaf_rn(lam * v.z, A4.z, -lm1 * B4.z);
            float a = fabsf(arg);
            res.z = copysignf(__log2f(a + __fsqrt_rn(__fmaf_rn(a, a, 1.0f))), arg) * S4.z;
        }
        {
            float arg = __fmaf_rn(lam * v.w, A4.w, -lm1 * B4.w);
            float a = fabsf(arg);
            res.w = copysignf(__log2f(a + __fsqrt_rn(__fmaf_rn(a, a, 1.0f))), arg) * S4.w;
        }
        outv[(j << 6) + l] = res;                    // fully-coalesced 1KB store
    }
}

extern "C" void kernel_launch(void* const* d_in, const int* in_sizes, int n_in,
                              void* d_out, int out_size, void* d_ws, size_t ws_size,
                              hipStream_t stream) {
    const float* x = (const float*)d_in[0];   // [16*8192, 128] fp32
    const float* z = (const float*)d_in[1];   // [128, 128] fp32
    const float* r = (const float*)d_in[2];   // [128] fp32
    float* out = (float*)d_out;

    // ws layout: zt_sw bf16 swizzled [128][128] (32768 B) | An[128] | Bn[128] | Sn[128]
    char* wsb = (char*)d_ws;
    unsigned short* zt_sw = (unsigned short*)wsb;
    float* An = (float*)(wsb + 128 * D * sizeof(unsigned short));
    float* Bn = An + 128;
    float* Sn = An + 256;

    hmlr_prep<<<128, 128, 0, stream>>>(z, r, zt_sw, An, Bn, Sn);

    const int n_rows = in_sizes[0] / D;       // 131072
    hmlr_main<<<n_rows / 64, 256, 0, stream>>>(x, zt_sw, An, Bn, Sn, out);
}

// Round 8
// 121.127 us; speedup vs baseline: 1.0007x; 1.0007x over previous
//
#include <hip/hip_runtime.h>
#include <cstdint>

// Poincare-ball MLR:  out[row][n] = S_n * asinh( lam_row * inner[row][n] * A_n - (lam_row-1) * B_n )
//   inner = X @ Z  (bf16 MFMA),  lam_row = 2/(1 - ||x_row||^2)
//   A_n = cosh(2 r_n)/znorm_n,  B_n = sinh(2 r_n),  S_n = 2 znorm_n   (c = 1)
//
// R7 = R6 + pre-barrier hoisting: the A-gathers (x), ssq shuffle-reduce, bf16
// pack, and epilogue constants touch no LDS, so they are issued BEFORE the
// __syncthreads that waits on the Zt global_load_lds DMA. Each wave's startup
// chain becomes max(Zt-DMA, A-load+pack) instead of their sum. Everything else
// identical to R6 (32KB LDS, 5 blocks/CU = 20 waves/CU, swizzled B-frags,
// LDS-transposed epilogue with 1KB coalesced stores).

typedef __attribute__((ext_vector_type(8))) short short8;   // 8 bf16 = 4 VGPRs (MFMA A/B frag)
typedef __attribute__((ext_vector_type(4))) float floatx4;  // MFMA C/D frag

#define D 128

__device__ inline unsigned bf16_rhu(float f) {   // round-half-up to bf16, bit trick (2 VALU)
    return (__float_as_uint(f) + 0x8000u) >> 16;
}
__device__ inline unsigned pack2(float lo, float hi) {
    return bf16_rhu(lo) | (bf16_rhu(hi) << 16);
}

// ---------------- prep: PRE-SWIZZLED bf16 Zt + per-col constant arrays ----------------
// zt_sw chunk layout: 16B chunk (row, c) stored at chunk index row*16 + (c ^ (row&7)),
// so a linear global_load_lds stage reproduces the swizzled LDS layout.
// An = cosh(2r)/zn, Bn = sinh(2r), Sn = 2*zn*ln2 (ln2 folded: asinh via log2)
__global__ void hmlr_prep(const float* __restrict__ z, const float* __restrict__ r,
                          unsigned short* __restrict__ zt_sw, float* __restrict__ An,
                          float* __restrict__ Bn, float* __restrict__ Sn) {
    int n = blockIdx.x;
    int k = threadIdx.x;
    float v = z[k * D + n];                          // column n of Z
    int c = k >> 3, p = k & 7;
    zt_sw[n * D + ((c ^ (n & 7)) << 3) + p] = (unsigned short)bf16_rhu(v);
    float pw = v * v;
    #pragma unroll
    for (int off = 32; off >= 1; off >>= 1) pw += __shfl_down(pw, off, 64);
    __shared__ float tmp[2];
    if ((k & 63) == 0) tmp[k >> 6] = pw;
    __syncthreads();
    if (k == 0) {
        float ss = tmp[0] + tmp[1];
        float zn = fmaxf(sqrtf(ss), 1e-15f);
        float tc = 2.0f * r[n];                      // 2*sqrt(c)*r, c=1
        An[n] = coshf(tc) / zn;
        Bn[n] = sinhf(tc);
        Sn[n] = 2.0f * zn * 0.69314718055994531f;
    }
}

// ---------------- main: 2048 blocks x 256 threads, 4 waves x 16 rows = 64 rows/block ------
__global__ __launch_bounds__(256, 5) void hmlr_main(const float* __restrict__ x,
                                                    const unsigned short* __restrict__ zt_sw,
                                                    const float* __restrict__ An,
                                                    const float* __restrict__ Bn,
                                                    const float* __restrict__ Sn,
                                                    float* __restrict__ out) {
    __shared__ __align__(16) unsigned char lds[32768];   // Zt (phase 1) / transpose buf (phase 2)

    const int t    = threadIdx.x;
    const int w    = t >> 6;         // wave 0..3
    const int l    = t & 63;
    const int quad = l >> 4;         // 0..3
    const int l15  = l & 15;
    const int l7   = l & 7;

    // ---- Zt -> LDS: async direct-to-LDS, issued first, waited at the barrier ----
#if __has_builtin(__builtin_amdgcn_global_load_lds)
    #pragma unroll
    for (int i = 0; i < 8; ++i) {
        int ci = w * 512 + i * 64 + l;               // 16B chunk index 0..2047
        __builtin_amdgcn_global_load_lds(
            (const __attribute__((address_space(1))) unsigned int*)(zt_sw + (ci << 3)),
            (__attribute__((address_space(3))) unsigned int*)(lds + ((w * 512 + i * 64) << 4)),
            16, 0, 0);
    }
#else
    #pragma unroll
    for (int i = 0; i < 8; ++i) {
        int ci = w * 512 + i * 64 + l;
        *reinterpret_cast<uint4*>(&lds[ci << 4]) = reinterpret_cast<const uint4*>(zt_sw)[ci];
    }
#endif

    // ======== pre-barrier phase: everything that does NOT touch LDS ========

    // ---- X direct from global in MFMA A-layout: lane(m=l15) reads row's k-octets ----
    const int rowbase = blockIdx.x * 64 + w * 16;    // this wave's 16 rows
    const float* xrow = x + (size_t)(rowbase + l15) * D + (quad << 3);
    float4 xv[8];
    #pragma unroll
    for (int kc = 0; kc < 4; ++kc) {
        xv[2 * kc]     = *reinterpret_cast<const float4*>(xrow + (kc << 5));
        xv[2 * kc + 1] = *reinterpret_cast<const float4*>(xrow + (kc << 5) + 4);
    }

    // ---- epilogue constants: global, LDS-independent -> issue early ----
    const int col0 = (l & 31) << 2;
    float4 A4 = *reinterpret_cast<const float4*>(An + col0);
    float4 B4 = *reinterpret_cast<const float4*>(Bn + col0);
    float4 S4 = *reinterpret_cast<const float4*>(Sn + col0);

    // ---- ||x_row||^2 fp32 (pre-cast): lane partial + combine quads sharing l15 ----
    float ssq = 0.f;
    #pragma unroll
    for (int i = 0; i < 8; ++i)
        ssq += xv[i].x * xv[i].x + xv[i].y * xv[i].y + xv[i].z * xv[i].z + xv[i].w * xv[i].w;
    ssq += __shfl_xor(ssq, 16);
    ssq += __shfl_xor(ssq, 32);      // lane l now holds ssq of row (rowbase + (l&15))

    // ---- bf16 A-frags, bit-trick pack ----
    short8 afrag[4];
    #pragma unroll
    for (int kc = 0; kc < 4; ++kc) {
        union { short8 s8; unsigned u[4]; } af;
        af.u[0] = pack2(xv[2 * kc].x,     xv[2 * kc].y);
        af.u[1] = pack2(xv[2 * kc].z,     xv[2 * kc].w);
        af.u[2] = pack2(xv[2 * kc + 1].x, xv[2 * kc + 1].y);
        af.u[3] = pack2(xv[2 * kc + 1].z, xv[2 * kc + 1].w);
        afrag[kc] = af.s8;
    }

    // ======== barrier: waits on the Zt DMA (and our already-landed x loads) ========
    __syncthreads();

    // ---- MFMA 16x16x32 bf16, per-kc B preload (8 frags in regs -> ILP) ----
    floatx4 acc[8];
    #pragma unroll
    for (int nt = 0; nt < 8; ++nt) acc[nt] = (floatx4){0.f, 0.f, 0.f, 0.f};

    #pragma unroll
    for (int kc = 0; kc < 4; ++kc) {
        short8 b[8];
        #pragma unroll
        for (int nt = 0; nt < 8; ++nt)
            b[nt] = *reinterpret_cast<const short8*>(
                &lds[((nt * 16 + l15) << 8) + (((quad + (kc << 2)) ^ l7) << 4)]);
        #pragma unroll
        for (int nt = 0; nt < 8; ++nt)
            acc[nt] = __builtin_amdgcn_mfma_f32_16x16x32_bf16(afrag[kc], b[nt], acc[nt], 0, 0, 0);
    }

    // ---- Zt region now dead for the whole block: recycle as per-wave transpose buffer ----
    __syncthreads();
    unsigned char* eb = lds + (w << 13);             // wave-private 8KB slice

    // scatter acc into transposed staging: row-major fp32 [16][128], XOR-swizzled
    // 16B chunks (chunk ^ (row&7)). Bank aliasing across the wave: exactly 2-way (free).
    #pragma unroll
    for (int reg = 0; reg < 4; ++reg) {
        int row = (quad << 2) + reg;
        int r7  = row & 7;
        #pragma unroll
        for (int nt = 0; nt < 8; ++nt) {
            int col  = l15 + (nt << 4);
            int byte = (row << 9) + (((col >> 2) ^ r7) << 4) + ((col & 3) << 2);
            *reinterpret_cast<float*>(&eb[byte]) = acc[nt][reg];
        }
    }

    // coalesced readback (same-wave DS ordering, no barrier) + asinh + 1KB stores
    float4* outv = reinterpret_cast<float4*>(out + (size_t)rowbase * D);
    #pragma unroll
    for (int j = 0; j < 8; ++j) {
        int rl = (j << 1) + (l >> 5);                // wave-local row 0..15
        float4 v = *reinterpret_cast<const float4*>(
            &eb[(rl << 9) + (((l & 31) ^ (rl & 7)) << 4)]);
        float rss = __shfl(ssq, rl);                 // row rl's ||x||^2 (bpermute)
        float lam = 2.0f / (1.0f - rss);
        float lm1 = lam - 1.0f;
        float4 res;
        {
            float arg = __fmaf_rn(lam * v.x, A4.x, -lm1 * B4.x);
            float a = fabsf(arg);
            res.x = copysignf(__log2f(a + __fsqrt_rn(__fmaf_rn(a, a, 1.0f))), arg) * S4.x;
        }
        {
            float arg = __fmaf_rn(lam * v.y, A4.y, -lm1 * B4.y);
            float a = fabsf(arg);
            res.y = copysignf(__log2f(a + __fsqrt_rn(__fmaf_rn(a, a, 1.0f))), arg) * S4.y;
        }
        {
            float arg = __fmaf_rn(lam * v.z, A4.z, -lm1 * B4.z);
            float a = fabsf(arg);
            res.z = copysignf(__log2f(a + __fsqrt_rn(__fmaf_rn(a, a, 1.0f))), arg) * S4.z;
        }
        {
            float arg = __fmaf_rn(lam * v.w, A4.w, -lm1 * B4.w);
            float a = fabsf(arg);
            res.w = copysignf(__log2f(a + __fsqrt_rn(__fmaf_rn(a, a, 1.0f))), arg) * S4.w;
        }
        outv[(j << 6) + l] = res;                    // fully-coalesced 1KB store
    }
}

extern "C" void kernel_launch(void* const* d_in, const int* in_sizes, int n_in,
                              void* d_out, int out_size, void* d_ws, size_t ws_size,
                              hipStream_t stream) {
    const float* x = (const float*)d_in[0];   // [16*8192, 128] fp32
    const float* z = (const float*)d_in[1];   // [128, 128] fp32
    const float* r = (const float*)d_in[2];   // [128] fp32
    float* out = (float*)d_out;

    // ws layout: zt_sw bf16 swizzled [128][128] (32768 B) | An[128] | Bn[128] | Sn[128]
    char* wsb = (char*)d_ws;
    unsigned short* zt_sw = (unsigned short*)wsb;
    float* An = (float*)(wsb + 128 * D * sizeof(unsigned short));
    float* Bn = An + 128;
    float* Sn = An + 256;

    hmlr_prep<<<128, 128, 0, stream>>>(z, r, zt_sw, An, Bn, Sn);

    const int n_rows = in_sizes[0] / D;       // 131072
    hmlr_main<<<n_rows / 64, 256, 0, stream>>>(x, zt_sw, An, Bn, Sn, out);
}